// Round 3
// baseline (5287.986 us; speedup 1.0000x reference)
//
#include <hip/hip_runtime.h>
#include <hip/hip_bf16.h>

#define Bn 32
#define Sn 400
#define Tn 100
#define Vn 32000
#define OOVn 100
#define VEn 32100
#define En 512
#define Un 256
#define AUn 256
#define GPn 256
#define ENCn 512
#define Z4n 1024

typedef __attribute__((ext_vector_type(8))) short bf16x8;
typedef __attribute__((ext_vector_type(4))) float f32x4;
typedef unsigned short ushort_t;
typedef unsigned long long u64;

__device__ __forceinline__ float rcp_f(float x){ return __builtin_amdgcn_rcpf(x); }
__device__ __forceinline__ float tanh_fast(float x){
  float e2 = __expf(2.f*x);
  return 1.f - 2.f*rcp_f(e2 + 1.f);
}
__device__ __forceinline__ float sigmoid_f(float x){ return 1.f/(1.f+__expf(-x)); }
__device__ __forceinline__ ushort_t f2bf(float f){
  unsigned u = __float_as_uint(f);
  unsigned r = (u + 0x7FFFu + ((u>>16)&1u)) >> 16;   // RNE
  return (ushort_t)r;
}
__device__ __forceinline__ u64 shfl_xor_u64(u64 v, int m){
  unsigned lo = (unsigned)v, hi = (unsigned)(v>>32);
  lo = (unsigned)__shfl_xor((int)lo, m);
  hi = (unsigned)__shfl_xor((int)hi, m);
  return ((u64)hi<<32)|(u64)lo;
}

// ---------------- pre-loop kernels ----------------

__global__ __launch_bounds__(256) void k_gather(const int* __restrict__ gt,
    const float* __restrict__ emb, float* __restrict__ Xall){
  int r = blockIdx.x;                 // r = t*32 + b
  int t = r >> 5, b = r & 31;
  int tok = gt[b*Tn + t];
  const float* src = emb + (size_t)tok*En;
  float* dst = Xall + (size_t)r*En;
  for (int i = threadIdx.x; i < En; i += 256) dst[i] = src[i];
}

// Zx = Xall @ Wk + bias   [3200,512]@[512,1024], f32 tiled 64x64
__global__ __launch_bounds__(256) void k_zx(const float* __restrict__ X,
    const float* __restrict__ Wk, const float* __restrict__ bias, float* __restrict__ Zx){
  __shared__ float As[64][17];
  __shared__ float Bs[16][65];
  int r0 = blockIdx.x * 64;
  int c0 = blockIdx.y * 64;
  int tid = threadIdx.x;
  int ty = tid >> 4, tx = tid & 15;
  float acc[4][4] = {};
  for (int k0 = 0; k0 < En; k0 += 16){
    #pragma unroll
    for (int p = 0; p < 4; ++p){
      int row = (tid>>4) + p*16, kk = tid & 15;
      As[row][kk] = X[(size_t)(r0+row)*En + k0 + kk];
    }
    #pragma unroll
    for (int p = 0; p < 4; ++p){
      int kk = (tid>>6) + p*4, cc = tid & 63;
      Bs[kk][cc] = Wk[(size_t)(k0+kk)*Z4n + c0 + cc];
    }
    __syncthreads();
    #pragma unroll
    for (int kk = 0; kk < 16; ++kk){
      float av[4], bv[4];
      #pragma unroll
      for (int i=0;i<4;++i) av[i] = As[ty*4+i][kk];
      #pragma unroll
      for (int j=0;j<4;++j) bv[j] = Bs[kk][tx*4+j];
      #pragma unroll
      for (int i=0;i<4;++i)
        #pragma unroll
        for (int j=0;j<4;++j) acc[i][j] += av[i]*bv[j];
    }
    __syncthreads();
  }
  #pragma unroll
  for (int i=0;i<4;++i){
    int row = r0 + ty*4 + i;
    #pragma unroll
    for (int j=0;j<4;++j){
      int col = c0 + tx*4 + j;
      Zx[(size_t)row*Z4n + col] = acc[i][j] + bias[col];
    }
  }
}

// gpx[t,:] = x[t,b=0,:] @ gp_Wi + gp_bi
__global__ __launch_bounds__(256) void k_gpx(const float* __restrict__ Xall,
    const float* __restrict__ Wi, const float* __restrict__ bi, float* __restrict__ gpx){
  int t = blockIdx.x, j = threadIdx.x;
  const float* x = Xall + (size_t)(t*Bn + 0)*En;
  float acc = bi[j];
  for (int u = 0; u < En; ++u) acc += x[u]*Wi[u*GPn + j];
  gpx[t*GPn + j] = acc;
}

// W2 [256][32000] f32 -> W2T [32000][256] bf16 (LDS-tiled transpose)
__global__ __launch_bounds__(256) void k_w2t(const float* __restrict__ W2,
    ushort_t* __restrict__ W2T){
  __shared__ float tile[64][65];
  int n0 = blockIdx.x * 64;   // 500
  int k0 = blockIdx.y * 64;   // 4
  int tx = threadIdx.x & 63, ty4 = threadIdx.x >> 6;
  #pragma unroll
  for (int i = 0; i < 16; ++i){
    int k = ty4 + i*4;
    tile[k][tx] = W2[(size_t)(k0+k)*Vn + n0 + tx];
  }
  __syncthreads();
  #pragma unroll
  for (int i = 0; i < 16; ++i){
    int n = ty4 + i*4;
    W2T[(size_t)(n0+n)*Un + k0 + tx] = f2bf(tile[tx][n]);
  }
}

// ---------------- persistent 256-block recurrent kernel ----------------
// Group g = 8 blocks per batch-row b. Block k of group owns:
//   LSTM h-cols [32k,32k+32) (Wr slice LDS-resident), dec cols [32k,32k+32),
//   attention s-rows [50k,50k+50) (cov slice in LDS).
// Inter-block sync: per-group monotonic atomic barrier (3 per step).

__global__ __launch_bounds__(1024, 1) void k_loop(
    const float* __restrict__ Zx, const float* __restrict__ Wr,
    const float* __restrict__ Wd, const float* __restrict__ bd,
    const float* __restrict__ Wc, const float* __restrict__ Wa,
    const float* __restrict__ enc_attn,
    const float* __restrict__ h0, const float* __restrict__ c0,
    float* __restrict__ h_all, float* __restrict__ c_cur,
    float* __restrict__ dec_cur, float* __restrict__ c0_all,
    float* __restrict__ a_all, float* __restrict__ covloss,
    float* __restrict__ psum, unsigned* __restrict__ bars){
  __shared__ float Wr_lds[256*128];     // 128 KB: Wr slice, cols {32k+i+256q}
  __shared__ float hc_lds[512];
  __shared__ float ppart[8][132];
  __shared__ float ppB[32][33];
  __shared__ float zfull[128];
  __shared__ float dec_lds[256];
  __shared__ float c_own[32];
  __shared__ float cov_lds[64];
  __shared__ float sc_lds[64];
  __shared__ float wred[16];
  __shared__ float redS[8];

  const int gid = blockIdx.x;
  const int b = gid >> 3, k = gid & 7;
  const int tid = threadIdx.x;
  const int lane = tid & 63, w = tid >> 6;
  unsigned* cnt = bars + b*32;          // 128B-strided slot per group

  // preload Wr slice into LDS (once)
  for (int idx = tid; idx < 256*128; idx += 1024){
    int u = idx >> 7, jl = idx & 127;
    int gcol = 32*k + (jl & 31) + 256*(jl >> 5);
    Wr_lds[idx] = Wr[(size_t)u*Z4n + gcol];
  }
  if (tid < 32) c_own[tid] = c0[b*Un + 32*k + tid];
  if (tid < 50) cov_lds[tid] = 0.f;
  // per-lane attention weight fragments
  const float4 wc4 = *(const float4*)(Wc + lane*4);
  const float4 wa4 = *(const float4*)(Wa + lane*4);
  __syncthreads();

  unsigned bar_target = 0;
  for (int t = 0; t < Tn; ++t){
    // ======== phase A: LSTM ========
    {
      const float* hsrc = (t == 0) ? (h0 + b*Un)
                                   : (h_all + (size_t)((t-1)*Bn + b)*Un);
      for (int i = tid; i < Un; i += 1024) hc_lds[i] = hsrc[i];
    }
    __syncthreads();
    {
      int jl = tid & 127, p = tid >> 7;
      float acc = 0.f;
      const float* wr = Wr_lds + (p*32)*128 + jl;
      const float* hb = hc_lds + p*32;
      #pragma unroll 8
      for (int uu = 0; uu < 32; ++uu) acc += hb[uu] * wr[(size_t)uu*128];
      ppart[p][jl] = acc;
    }
    __syncthreads();
    if (tid < 128){
      float s = 0.f;
      #pragma unroll
      for (int q = 0; q < 8; ++q) s += ppart[q][tid];
      int gcol = 32*k + (tid & 31) + 256*(tid >> 5);
      zfull[tid] = s + Zx[(size_t)(t*Bn + b)*Z4n + gcol];
    }
    __syncthreads();
    if (tid < 32){
      float zi = zfull[tid], zf = zfull[32+tid], zg = zfull[64+tid], zo = zfull[96+tid];
      float cn = sigmoid_f(zf)*c_own[tid] + sigmoid_f(zi)*tanhf(zg);
      float hn = sigmoid_f(zo)*tanhf(cn);
      c_own[tid] = cn;
      int col = 32*k + tid;
      h_all[(size_t)(t*Bn + b)*Un + col] = hn;
      c_cur[b*Un + col] = cn;
      if (b == 0) c0_all[t*Un + col] = cn;
    }
    // ---- barrier A ----
    bar_target += 8;
    __syncthreads();
    if (tid == 0){
      __threadfence();
      __hip_atomic_fetch_add(cnt, 1u, __ATOMIC_RELEASE, __HIP_MEMORY_SCOPE_AGENT);
      while (__hip_atomic_load(cnt, __ATOMIC_ACQUIRE, __HIP_MEMORY_SCOPE_AGENT) < bar_target)
        __builtin_amdgcn_s_sleep(2);
      __threadfence();
    }
    __syncthreads();

    // ======== phase B: dec_attn cols [32k,32k+32) ========
    for (int i = tid; i < 512; i += 1024)
      hc_lds[i] = (i < Un) ? h_all[(size_t)(t*Bn + b)*Un + i]
                           : c_cur[b*Un + i - Un];
    __syncthreads();
    {
      int cc = tid & 31, pp = tid >> 5;    // 32 slices x 16 u
      float acc = 0.f;
      const float* wd = Wd + (size_t)(pp*16)*AUn + 32*k + cc;
      const float* hb = hc_lds + pp*16;
      #pragma unroll
      for (int uu = 0; uu < 16; ++uu) acc += hb[uu] * wd[(size_t)uu*AUn];
      ppB[pp][cc] = acc;
    }
    __syncthreads();
    if (tid < 32){
      float s = 0.f;
      #pragma unroll
      for (int q = 0; q < 32; ++q) s += ppB[q][tid];
      int j = 32*k + tid;
      dec_cur[b*AUn + j] = s + bd[j];
    }
    // ---- barrier B ----
    bar_target += 8;
    __syncthreads();
    if (tid == 0){
      __threadfence();
      __hip_atomic_fetch_add(cnt, 1u, __ATOMIC_RELEASE, __HIP_MEMORY_SCOPE_AGENT);
      while (__hip_atomic_load(cnt, __ATOMIC_ACQUIRE, __HIP_MEMORY_SCOPE_AGENT) < bar_target)
        __builtin_amdgcn_s_sleep(2);
      __threadfence();
    }
    __syncthreads();

    // ======== phase C: scores + exp for s-rows [50k,50k+50) ========
    for (int i = tid; i < AUn; i += 1024) dec_lds[i] = dec_cur[b*AUn + i];
    __syncthreads();
    {
      const float4 da = *(const float4*)(dec_lds + lane*4);
      float wsum = 0.f;
      for (int sl = w; sl < 50; sl += 16){
        int s = 50*k + sl;
        float cvv = cov_lds[sl];
        const float4 e = *(const float4*)(enc_attn + ((size_t)(b*Sn + s))*AUn + lane*4);
        float psc = tanh_fast(e.x + cvv*wc4.x + da.x)*wa4.x
                  + tanh_fast(e.y + cvv*wc4.y + da.y)*wa4.y
                  + tanh_fast(e.z + cvv*wc4.z + da.z)*wa4.z
                  + tanh_fast(e.w + cvv*wc4.w + da.w)*wa4.w;
        #pragma unroll
        for (int m = 1; m < 64; m <<= 1) psc += __shfl_xor(psc, m);
        if (lane == 0){
          float ev = __expf(psc);
          sc_lds[sl] = ev;
          wsum += ev;
        }
      }
      if (lane == 0) wred[w] = wsum;
    }
    __syncthreads();
    if (tid == 0){
      float S = 0.f;
      #pragma unroll
      for (int q = 0; q < 16; ++q) S += wred[q];
      psum[b*8 + k] = S;
    }
    // ---- barrier C ----
    bar_target += 8;
    __syncthreads();
    if (tid == 0){
      __threadfence();
      __hip_atomic_fetch_add(cnt, 1u, __ATOMIC_RELEASE, __HIP_MEMORY_SCOPE_AGENT);
      while (__hip_atomic_load(cnt, __ATOMIC_ACQUIRE, __HIP_MEMORY_SCOPE_AGENT) < bar_target)
        __builtin_amdgcn_s_sleep(2);
      __threadfence();
    }
    __syncthreads();

    // ======== phase D: normalize + cov update (no trailing barrier) ========
    if (tid < 8) redS[tid] = psum[b*8 + tid];
    __syncthreads();
    if (tid < 64){
      float S = redS[0]+redS[1]+redS[2]+redS[3]+redS[4]+redS[5]+redS[6]+redS[7];
      float inv = 1.f / S;
      float clp = 0.f;
      if (tid < 50){
        float aa = sc_lds[tid] * inv;
        float co = cov_lds[tid];
        a_all[(size_t)(t*Bn + b)*Sn + 50*k + tid] = aa;
        clp = fminf(co, aa);
        cov_lds[tid] = co + aa;
      }
      #pragma unroll
      for (int m = 1; m < 64; m <<= 1) clp += __shfl_xor(clp, m);
      if (tid == 0) atomicAdd(&covloss[b*Tn + t], clp);
    }
    // safe: next write to sc_lds/cov_lds happens after barrier B/C of t+1
  }
}

// ---------------- post-loop kernels ----------------

// hid = h_all @ W1 + b1 -> bf16    (block per t)
__global__ __launch_bounds__(256) void k_hid(const float* __restrict__ h_all,
    const float* __restrict__ W1, const float* __restrict__ b1, ushort_t* __restrict__ hid){
  __shared__ float hl[Bn*Un];
  int t = blockIdx.x, tid = threadIdx.x;
  for (int i = tid; i < Bn*Un; i += 256) hl[i] = h_all[(size_t)t*Bn*Un + i];
  __syncthreads();
  int j = tid;
  float bj = b1[j];
  float acc[32];
  #pragma unroll
  for (int r = 0; r < 32; ++r) acc[r] = bj;
  for (int u = 0; u < Un; ++u){
    float wv = W1[u*Un + j];
    #pragma unroll
    for (int r = 0; r < 32; ++r) acc[r] += hl[r*Un + u]*wv;
  }
  #pragma unroll
  for (int r = 0; r < 32; ++r) hid[(size_t)(t*Bn + r)*Un + j] = f2bf(acc[r]);
}

// pg[t] via row-0 quirk
__global__ __launch_bounds__(256) void k_pg(const float* __restrict__ a_all,
    const float* __restrict__ enc_out, const float* __restrict__ h_all,
    const float* __restrict__ c0_all, const float* __restrict__ gpWs,
    const float* __restrict__ gpWc, const float* __restrict__ gpx,
    const float* __restrict__ gpWg, float* __restrict__ pg){
  __shared__ float al[Sn];
  __shared__ float cv[ENCn];
  __shared__ float red[4];
  int t = blockIdx.x, tid = threadIdx.x;
  for (int s = tid; s < Sn; s += 256) al[s] = a_all[(size_t)(t*Bn + 0)*Sn + s];
  __syncthreads();
  for (int e = tid; e < ENCn; e += 256){
    float acc = 0.f;
    for (int s = 0; s < Sn; ++s) acc += enc_out[(size_t)s*ENCn + e]*al[s];
    cv[e] = acc;
  }
  __syncthreads();
  int j = tid;
  float g = gpx[t*GPn + j];
  const float* h0r = h_all + (size_t)t*Bn*Un;       // b = 0 row
  const float* c0r = c0_all + t*Un;
  for (int u = 0; u < Un; ++u) g += h0r[u]*gpWs[u*GPn + j];
  for (int u = 0; u < Un; ++u) g += c0r[u]*gpWs[(Un+u)*GPn + j];
  for (int e = 0; e < ENCn; ++e) g += cv[e]*gpWc[e*GPn + j];
  float v = g * gpWg[j];
  int lane = tid & 63, wv2 = tid >> 6;
  #pragma unroll
  for (int m = 1; m < 64; m <<= 1) v += __shfl_xor(v, m);
  if (lane == 0) red[wv2] = v;
  __syncthreads();
  if (tid == 0) pg[t] = 1.f/(1.f+__expf(-(red[0]+red[1]+red[2]+red[3])));
}

// GEMM: A = hid [3200][256] bf16, B = W2T [32000][256] bf16.
// mode 0: Ssum[r] += sum_v exp(logit);  mode 1: probs = pg*exp/S (+OOV zeros) + amax
__global__ __launch_bounds__(256) void k_gemm(const ushort_t* __restrict__ A,
    const ushort_t* __restrict__ Bw, const float* __restrict__ b2,
    float* __restrict__ Ssum, u64* __restrict__ amax, const float* __restrict__ pg,
    float* __restrict__ probs, int mode){
  int r0 = blockIdx.x * 64;
  int n0 = blockIdx.y * 256;
  int tid = threadIdx.x;
  if (mode == 1 && n0 >= Vn){
    for (int idx = tid; idx < 64*OOVn; idx += 256){
      int i = idx/OOVn, vv = idx%OOVn;
      int r = r0+i; int tt = r>>5, bb = r&31;
      probs[(size_t)(bb*Tn+tt)*VEn + Vn + vv] = 0.f;
    }
    return;
  }
  __shared__ ushort_t Bs[64*264];          // [64 n][256 k + pad8]
  int lane = tid & 63, w = tid >> 6;
  bf16x8 af[8];
  {
    const ushort_t* ar = A + (size_t)(r0 + w*16 + (lane&15))*Un + (lane>>4)*8;
    #pragma unroll
    for (int kk = 0; kk < 8; ++kk) af[kk] = *(const bf16x8*)(ar + kk*32);
  }
  f32x4 acc[16];
  #pragma unroll
  for (int i = 0; i < 16; ++i) acc[i] = (f32x4){0.f,0.f,0.f,0.f};

  for (int nsub = 0; nsub < 4; ++nsub){
    __syncthreads();
    {
      const ushort_t* gb = Bw + (size_t)(n0 + nsub*64)*Un;
      #pragma unroll
      for (int i = 0; i < 8; ++i){
        int chunk = tid + i*256;
        int rr = chunk >> 5, cc = chunk & 31;
        uint4 d = *(const uint4*)(gb + rr*Un + cc*8);
        *(uint4*)(Bs + rr*264 + cc*8) = d;
      }
    }
    __syncthreads();
    #pragma unroll
    for (int kk = 0; kk < 8; ++kk){
      #pragma unroll
      for (int ntl = 0; ntl < 4; ++ntl){
        bf16x8 bf = *(const bf16x8*)(Bs + (ntl*16 + (lane&15))*264 + kk*32 + (lane>>4)*8);
        acc[nsub*4+ntl] = __builtin_amdgcn_mfma_f32_16x16x32_bf16(af[kk], bf, acc[nsub*4+ntl], 0, 0, 0);
      }
    }
  }

  int rowloc = w*16 + (lane>>4)*4;
  if (mode == 0){
    float rs[4] = {0.f,0.f,0.f,0.f};
    #pragma unroll
    for (int nt = 0; nt < 16; ++nt){
      int v = n0 + (nt>>2)*64 + (nt&3)*16 + (lane&15);
      float bb = b2[v];
      #pragma unroll
      for (int i = 0; i < 4; ++i) rs[i] += __expf(acc[nt][i] + bb);
    }
    #pragma unroll
    for (int m = 1; m < 16; m <<= 1)
      #pragma unroll
      for (int i = 0; i < 4; ++i) rs[i] += __shfl_xor(rs[i], m);
    if ((lane&15) == 0)
      #pragma unroll
      for (int i = 0; i < 4; ++i) atomicAdd(&Ssum[r0+rowloc+i], rs[i]);
  } else {
    float sc[4]; size_t obase[4];
    #pragma unroll
    for (int i = 0; i < 4; ++i){
      int r = r0+rowloc+i; int tt = r>>5, bb = r&31;
      sc[i] = pg[tt] / Ssum[r];
      obase[i] = (size_t)(bb*Tn+tt)*VEn;
    }
    u64 pm[4] = {0,0,0,0};
    #pragma unroll
    for (int nt = 0; nt < 16; ++nt){
      int v = n0 + (nt>>2)*64 + (nt&3)*16 + (lane&15);
      float bb = b2[v];
      #pragma unroll
      for (int i = 0; i < 4; ++i){
        float val = __expf(acc[nt][i] + bb) * sc[i];
        probs[obase[i] + v] = val;
        u64 p = ((u64)__float_as_uint(val)<<32) | (u64)(0xFFFFFFFFu - (unsigned)v);
        pm[i] = p > pm[i] ? p : pm[i];
      }
    }
    #pragma unroll
    for (int m = 1; m < 16; m <<= 1)
      #pragma unroll
      for (int i = 0; i < 4; ++i){
        u64 o = shfl_xor_u64(pm[i], m);
        pm[i] = o > pm[i] ? o : pm[i];
      }
    if ((lane&15) == 0)
      #pragma unroll
      for (int i = 0; i < 4; ++i) atomicMax(&amax[r0+rowloc+i], pm[i]);
  }
}

// scatter copy-dist into probs (deduped single-writer) + update amax
__global__ __launch_bounds__(256) void k_scatter(const int* __restrict__ ext,
    const float* __restrict__ a_all, const float* __restrict__ pg,
    float* __restrict__ probs, u64* __restrict__ amax){
  __shared__ int tok[Sn];
  __shared__ float val[Sn];
  int r = blockIdx.x; int t = r>>5, b = r&31;
  float c1 = 1.f - pg[t];
  int tid = threadIdx.x;
  for (int s = tid; s < Sn; s += 256){
    tok[s] = ext[b*Sn + s];
    val[s] = c1 * a_all[(size_t)r*Sn + s];
  }
  __syncthreads();
  size_t obase = (size_t)(b*Tn + t)*VEn;
  for (int s = tid; s < Sn; s += 256){
    int tk = tok[s];
    bool leader = true;
    float tot = 0.f;
    for (int s2 = 0; s2 < Sn; ++s2){
      if (tok[s2] == tk){
        if (s2 < s){ leader = false; break; }
        tot += val[s2];
      }
    }
    if (leader){
      float nv = probs[obase + tk] + tot;
      probs[obase + tk] = nv;
      u64 p = ((u64)__float_as_uint(nv)<<32) | (u64)(0xFFFFFFFFu - (unsigned)tk);
      atomicMax(&amax[r], p);
    }
  }
}

__global__ __launch_bounds__(256) void k_seqout(const u64* __restrict__ amax,
    float* __restrict__ seqs){
  int r = blockIdx.x*256 + threadIdx.x;
  if (r >= Tn*Bn) return;
  int t = r>>5, b = r&31;
  unsigned tk = 0xFFFFFFFFu - (unsigned)(amax[r] & 0xFFFFFFFFull);
  seqs[b*Tn + t] = (float)tk;
}

// ---------------- host launch ----------------

extern "C" void kernel_launch(void* const* d_in, const int* in_sizes, int n_in,
                              void* d_out, int out_size, void* d_ws, size_t ws_size,
                              hipStream_t stream){
  (void)in_sizes; (void)n_in; (void)out_size; (void)ws_size;
  const int*   gt       = (const int*)d_in[0];
  const int*   ext      = (const int*)d_in[1];
  const float* enc_out  = (const float*)d_in[2];
  const float* enc_attn = (const float*)d_in[3];
  const float* h0       = (const float*)d_in[4];
  const float* c0       = (const float*)d_in[5];
  const float* emb      = (const float*)d_in[6];
  const float* Wk       = (const float*)d_in[7];
  const float* Wr       = (const float*)d_in[8];
  const float* lb       = (const float*)d_in[9];
  const float* Wd       = (const float*)d_in[10];
  const float* bd       = (const float*)d_in[11];
  const float* Wc       = (const float*)d_in[12];
  const float* Wa       = (const float*)d_in[13];
  const float* W1       = (const float*)d_in[14];
  const float* b1       = (const float*)d_in[15];
  const float* W2       = (const float*)d_in[16];
  const float* b2       = (const float*)d_in[17];
  const float* gpWs     = (const float*)d_in[18];
  const float* gpWc     = (const float*)d_in[19];
  const float* gpWi     = (const float*)d_in[20];
  const float* gpbi     = (const float*)d_in[21];
  const float* gpWg     = (const float*)d_in[22];

  float* probs   = (float*)d_out;
  float* seqs    = probs + (size_t)Bn*Tn*VEn;
  float* covloss = seqs + Bn*Tn;

  char* wp = (char*)d_ws;
  auto carve = [&](size_t bytes)->void*{
    void* p = (void*)wp; wp += (bytes + 255) & ~(size_t)255; return p;
  };
  float*    Xall    = (float*)carve((size_t)3200*En*4);
  float*    Zx      = (float*)carve((size_t)3200*Z4n*4);
  float*    gpx     = (float*)carve((size_t)Tn*GPn*4);
  float*    h_all   = (float*)carve((size_t)Tn*Bn*Un*4);
  float*    c_cur   = (float*)carve((size_t)Bn*Un*4);
  float*    dec_cur = (float*)carve((size_t)Bn*AUn*4);
  float*    c0_all  = (float*)carve((size_t)Tn*Un*4);
  float*    a_all   = (float*)carve((size_t)3200*Sn*4);
  ushort_t* hid_bf  = (ushort_t*)carve((size_t)3200*Un*2);
  ushort_t* W2T     = (ushort_t*)carve((size_t)Vn*Un*2);
  float*    Ssum    = (float*)carve((size_t)3200*4);
  u64*      amax    = (u64*)carve((size_t)3200*8);
  float*    pg      = (float*)carve((size_t)Tn*4);
  float*    psum    = (float*)carve((size_t)Bn*8*4);
  unsigned* bars    = (unsigned*)carve((size_t)Bn*32*4);

  hipMemsetAsync(Ssum, 0, 3200*4, stream);
  hipMemsetAsync(amax, 0, 3200*8, stream);
  hipMemsetAsync(bars, 0, Bn*32*4, stream);
  hipMemsetAsync(covloss, 0, Bn*Tn*4, stream);

  k_gather<<<3200, 256, 0, stream>>>(gt, emb, Xall);
  k_zx    <<<dim3(50,16), 256, 0, stream>>>(Xall, Wk, lb, Zx);
  k_gpx   <<<Tn, 256, 0, stream>>>(Xall, gpWi, gpbi, gpx);
  k_w2t   <<<dim3(500,4), 256, 0, stream>>>(W2, W2T);

  k_loop  <<<256, 1024, 0, stream>>>(Zx, Wr, Wd, bd, Wc, Wa, enc_attn,
                                     h0, c0, h_all, c_cur, dec_cur, c0_all,
                                     a_all, covloss, psum, bars);

  k_hid <<<Tn, 256, 0, stream>>>(h_all, W1, b1, hid_bf);
  k_pg  <<<Tn, 256, 0, stream>>>(a_all, enc_out, h_all, c0_all, gpWs, gpWc, gpx, gpWg, pg);
  k_gemm<<<dim3(50,125), 256, 0, stream>>>(hid_bf, W2T, b2, Ssum, amax, pg, probs, 0);
  k_gemm<<<dim3(50,126), 256, 0, stream>>>(hid_bf, W2T, b2, Ssum, amax, pg, probs, 1);
  k_scatter<<<3200, 256, 0, stream>>>(ext, a_all, pg, probs, amax);
  k_seqout <<<13, 256, 0, stream>>>(amax, seqs);
}

// Round 4
// 2657.127 us; speedup vs baseline: 1.9901x; 1.9901x over previous
//
#include <hip/hip_runtime.h>
#include <hip/hip_bf16.h>

#define Bn 32
#define Sn 400
#define Tn 100
#define Vn 32000
#define OOVn 100
#define VEn 32100
#define En 512
#define Un 256
#define AUn 256
#define GPn 256
#define ENCn 512
#define Z4n 1024

typedef __attribute__((ext_vector_type(8))) short bf16x8;
typedef __attribute__((ext_vector_type(4))) float f32x4;
typedef unsigned short ushort_t;
typedef unsigned long long u64;

__device__ __forceinline__ float rcp_f(float x){ return __builtin_amdgcn_rcpf(x); }
__device__ __forceinline__ float tanh_fast(float x){
  float e2 = __expf(2.f*x);
  return 1.f - 2.f*rcp_f(e2 + 1.f);
}
__device__ __forceinline__ float sigmoid_f(float x){ return 1.f/(1.f+__expf(-x)); }
__device__ __forceinline__ ushort_t f2bf(float f){
  unsigned u = __float_as_uint(f);
  unsigned r = (u + 0x7FFFu + ((u>>16)&1u)) >> 16;   // RNE
  return (ushort_t)r;
}
__device__ __forceinline__ u64 shfl_xor_u64(u64 v, int m){
  unsigned lo = (unsigned)v, hi = (unsigned)(v>>32);
  lo = (unsigned)__shfl_xor((int)lo, m);
  hi = (unsigned)__shfl_xor((int)hi, m);
  return ((u64)hi<<32)|(u64)lo;
}

// ---------------- pre-loop kernels ----------------

__global__ __launch_bounds__(256) void k_gather(const int* __restrict__ gt,
    const float* __restrict__ emb, float* __restrict__ Xall){
  int r = blockIdx.x;                 // r = t*32 + b
  int t = r >> 5, b = r & 31;
  int tok = gt[b*Tn + t];
  const float* src = emb + (size_t)tok*En;
  float* dst = Xall + (size_t)r*En;
  for (int i = threadIdx.x; i < En; i += 256) dst[i] = src[i];
}

// Zx = Xall @ Wk + bias   [3200,512]@[512,1024], f32 tiled 64x64
__global__ __launch_bounds__(256) void k_zx(const float* __restrict__ X,
    const float* __restrict__ Wk, const float* __restrict__ bias, float* __restrict__ Zx){
  __shared__ float As[64][17];
  __shared__ float Bs[16][65];
  int r0 = blockIdx.x * 64;
  int c0 = blockIdx.y * 64;
  int tid = threadIdx.x;
  int ty = tid >> 4, tx = tid & 15;
  float acc[4][4] = {};
  for (int k0 = 0; k0 < En; k0 += 16){
    #pragma unroll
    for (int p = 0; p < 4; ++p){
      int row = (tid>>4) + p*16, kk = tid & 15;
      As[row][kk] = X[(size_t)(r0+row)*En + k0 + kk];
    }
    #pragma unroll
    for (int p = 0; p < 4; ++p){
      int kk = (tid>>6) + p*4, cc = tid & 63;
      Bs[kk][cc] = Wk[(size_t)(k0+kk)*Z4n + c0 + cc];
    }
    __syncthreads();
    #pragma unroll
    for (int kk = 0; kk < 16; ++kk){
      float av[4], bv[4];
      #pragma unroll
      for (int i=0;i<4;++i) av[i] = As[ty*4+i][kk];
      #pragma unroll
      for (int j=0;j<4;++j) bv[j] = Bs[kk][tx*4+j];
      #pragma unroll
      for (int i=0;i<4;++i)
        #pragma unroll
        for (int j=0;j<4;++j) acc[i][j] += av[i]*bv[j];
    }
    __syncthreads();
  }
  #pragma unroll
  for (int i=0;i<4;++i){
    int row = r0 + ty*4 + i;
    #pragma unroll
    for (int j=0;j<4;++j){
      int col = c0 + tx*4 + j;
      Zx[(size_t)row*Z4n + col] = acc[i][j] + bias[col];
    }
  }
}

// gpx[t,:] = x[t,b=0,:] @ gp_Wi + gp_bi
__global__ __launch_bounds__(256) void k_gpx(const float* __restrict__ Xall,
    const float* __restrict__ Wi, const float* __restrict__ bi, float* __restrict__ gpx){
  int t = blockIdx.x, j = threadIdx.x;
  const float* x = Xall + (size_t)(t*Bn + 0)*En;
  float acc = bi[j];
  for (int u = 0; u < En; ++u) acc += x[u]*Wi[u*GPn + j];
  gpx[t*GPn + j] = acc;
}

// W2 [256][32000] f32 -> W2T [32000][256] bf16 (LDS-tiled transpose)
__global__ __launch_bounds__(256) void k_w2t(const float* __restrict__ W2,
    ushort_t* __restrict__ W2T){
  __shared__ float tile[64][65];
  int n0 = blockIdx.x * 64;   // 500
  int k0 = blockIdx.y * 64;   // 4
  int tx = threadIdx.x & 63, ty4 = threadIdx.x >> 6;
  #pragma unroll
  for (int i = 0; i < 16; ++i){
    int k = ty4 + i*4;
    tile[k][tx] = W2[(size_t)(k0+k)*Vn + n0 + tx];
  }
  __syncthreads();
  #pragma unroll
  for (int i = 0; i < 16; ++i){
    int n = ty4 + i*4;
    W2T[(size_t)(n0+n)*Un + k0 + tx] = f2bf(tile[tx][n]);
  }
}

// ---------------- persistent 256-block recurrent kernel ----------------
// b = blockIdx&31, k = blockIdx>>5  -> all 8 blocks of group b share
// blockIdx mod 8, i.e. one XCD under the round-robin mapping (speed heuristic;
// correctness from agent-scope release/acquire only).
// Block k owns: LSTM h-cols [32k,32k+32) (Wr slice LDS-resident),
//   dec-attn PARTIAL over its own h/c rows, attention s-rows [50k,50k+50).
// 2 flag-barriers per step; no atomics RMW, no threadfence.

__global__ __launch_bounds__(1024, 1) void k_loop(
    const float* __restrict__ Zx, const float* __restrict__ Wr,
    const float* __restrict__ Wd, const float* __restrict__ bd,
    const float* __restrict__ Wc, const float* __restrict__ Wa,
    const float* __restrict__ enc_attn,
    const float* __restrict__ h0, const float* __restrict__ c0,
    float* __restrict__ h_all, float* __restrict__ decp,
    float* __restrict__ c0_all, float* __restrict__ a_all,
    float* __restrict__ covloss, float* __restrict__ psum,
    unsigned* __restrict__ bars){
  __shared__ float Wr_lds[256*128];     // 128 KB: Wr cols {32k+i+256q}
  __shared__ float hprev[Un];
  __shared__ float ppart[8][132];
  __shared__ float zfull[128];
  __shared__ float hnew[32], cown[32];
  __shared__ float ppB[4][260];
  __shared__ float dec_lds[AUn];
  __shared__ float cov_lds[64], sc_lds[64];
  __shared__ float wred[16];
  __shared__ float psred[8];

  const int b = blockIdx.x & 31, k = blockIdx.x >> 5;
  const int tid = threadIdx.x, lane = tid & 63, w = tid >> 6;
  unsigned* flags = bars + b*8*32;          // 8 slots, 128 B apart
  unsigned* myflag = flags + k*32;

  for (int idx = tid; idx < 256*128; idx += 1024){
    int u = idx >> 7, jl = idx & 127;
    int gcol = 32*k + (jl & 31) + 256*(jl >> 5);
    Wr_lds[idx] = Wr[(size_t)u*Z4n + gcol];
  }
  if (tid < 32) cown[tid] = c0[b*Un + 32*k + tid];
  if (tid < 50) cov_lds[tid] = 0.f;
  const float4 wc4 = *(const float4*)(Wc + lane*4);
  const float4 wa4 = *(const float4*)(Wa + lane*4);
  __syncthreads();

  for (int t = 0; t < Tn; ++t){
    // ======== phase A: LSTM slice + dec partials ========
    {
      const float* hsrc = (t == 0) ? (h0 + b*Un)
                                   : (h_all + (size_t)((t-1)*Bn + b)*Un);
      if (tid < Un) hprev[tid] = hsrc[tid];
    }
    __syncthreads();
    {
      int jl = tid & 127, p = tid >> 7;
      float acc = 0.f;
      const float* wr = Wr_lds + (p*32)*128 + jl;
      const float* hb = hprev + p*32;
      #pragma unroll 8
      for (int uu = 0; uu < 32; ++uu) acc += hb[uu] * wr[uu*128];
      ppart[p][jl] = acc;
    }
    __syncthreads();
    if (tid < 128){
      float s = 0.f;
      #pragma unroll
      for (int q = 0; q < 8; ++q) s += ppart[q][tid];
      int gcol = 32*k + (tid & 31) + 256*(tid >> 5);
      zfull[tid] = s + Zx[(size_t)(t*Bn + b)*Z4n + gcol];
    }
    __syncthreads();
    if (tid < 32){
      float zi = zfull[tid], zf = zfull[32+tid], zg = zfull[64+tid], zo = zfull[96+tid];
      float cn = sigmoid_f(zf)*cown[tid] + sigmoid_f(zi)*tanhf(zg);
      float hn = sigmoid_f(zo)*tanhf(cn);
      cown[tid] = cn; hnew[tid] = hn;
      int col = 32*k + tid;
      h_all[(size_t)(t*Bn + b)*Un + col] = hn;
      if (b == 0) c0_all[t*Un + col] = cn;
    }
    __syncthreads();
    {   // dec partial over own 64 rows (32 h + 32 c)
      int j = tid & 255, p = tid >> 8;
      int r0 = (p & 1)*16;
      const float* sb = ((p < 2) ? hnew : cown) + r0;
      int urow = (p < 2) ? (32*k + r0) : (Un + 32*k + r0);
      const float* wd = Wd + (size_t)urow*AUn + j;
      float acc = 0.f;
      #pragma unroll
      for (int uu = 0; uu < 16; ++uu) acc += sb[uu] * wd[(size_t)uu*AUn];
      ppB[p][j] = acc;
    }
    __syncthreads();
    if (tid < 256)
      decp[(size_t)(b*8 + k)*256 + tid] = ppB[0][tid]+ppB[1][tid]+ppB[2][tid]+ppB[3][tid];
    // ---- barrier 1 (publishes h_all slice + decp) ----
    {
      unsigned p1 = 2*(unsigned)t + 1;
      __syncthreads();   // drains all global stores (vmcnt) before flag
      if (tid == 0)
        __hip_atomic_store(myflag, p1, __ATOMIC_RELEASE, __HIP_MEMORY_SCOPE_AGENT);
      if (tid < 8){
        while (__hip_atomic_load(flags + tid*32, __ATOMIC_ACQUIRE,
                                 __HIP_MEMORY_SCOPE_AGENT) < p1)
          __builtin_amdgcn_s_sleep(1);
      }
      __syncthreads();
    }
    // ======== phase C: dec sum + scores + exp-partials ========
    if (tid < 256){
      float s = bd[tid];
      const float* dp = decp + (size_t)b*8*256 + tid;
      #pragma unroll
      for (int q = 0; q < 8; ++q) s += dp[q*256];
      dec_lds[tid] = s;
    }
    __syncthreads();
    {
      const float4 da = *(const float4*)(dec_lds + lane*4);
      float wsum = 0.f;
      for (int sl = w; sl < 50; sl += 16){
        int s = 50*k + sl;
        float cvv = cov_lds[sl];
        const float4 e = *(const float4*)(enc_attn + ((size_t)(b*Sn + s))*AUn + lane*4);
        float psc = tanh_fast(e.x + cvv*wc4.x + da.x)*wa4.x
                  + tanh_fast(e.y + cvv*wc4.y + da.y)*wa4.y
                  + tanh_fast(e.z + cvv*wc4.z + da.z)*wa4.z
                  + tanh_fast(e.w + cvv*wc4.w + da.w)*wa4.w;
        #pragma unroll
        for (int m = 1; m < 64; m <<= 1) psc += __shfl_xor(psc, m);
        if (lane == 0){
          float ev = __expf(psc);
          sc_lds[sl] = ev;
          wsum += ev;
        }
      }
      if (lane == 0) wred[w] = wsum;
    }
    __syncthreads();
    if (tid == 0){
      float S = 0.f;
      #pragma unroll
      for (int q = 0; q < 16; ++q) S += wred[q];
      psum[b*8 + k] = S;
    }
    // ---- barrier 2 (publishes psum) ----
    {
      unsigned p2 = 2*(unsigned)t + 2;
      __syncthreads();
      if (tid == 0)
        __hip_atomic_store(myflag, p2, __ATOMIC_RELEASE, __HIP_MEMORY_SCOPE_AGENT);
      if (tid < 8){
        while (__hip_atomic_load(flags + tid*32, __ATOMIC_ACQUIRE,
                                 __HIP_MEMORY_SCOPE_AGENT) < p2)
          __builtin_amdgcn_s_sleep(1);
      }
      __syncthreads();
    }
    // ======== phase D: normalize + cov update (no trailing barrier) ========
    if (tid < 8) psred[tid] = psum[b*8 + tid];
    __syncthreads();
    if (tid < 64){
      float S = psred[0]+psred[1]+psred[2]+psred[3]+psred[4]+psred[5]+psred[6]+psred[7];
      float inv = 1.f / S;
      float clp = 0.f;
      if (tid < 50){
        float aa = sc_lds[tid] * inv;
        float co = cov_lds[tid];
        a_all[(size_t)(t*Bn + b)*Sn + 50*k + tid] = aa;
        clp = fminf(co, aa);
        cov_lds[tid] = co + aa;
      }
      #pragma unroll
      for (int m = 1; m < 64; m <<= 1) clp += __shfl_xor(clp, m);
      if (tid == 0) atomicAdd(&covloss[b*Tn + t], clp);
    }
    // next writes to sc_lds/cov_lds/decp/psum all sit behind the next barriers
  }
}

// ---------------- post-loop kernels ----------------

// hid = h_all @ W1 + b1 -> bf16    (block per t)
__global__ __launch_bounds__(256) void k_hid(const float* __restrict__ h_all,
    const float* __restrict__ W1, const float* __restrict__ b1, ushort_t* __restrict__ hid){
  __shared__ float hl[Bn*Un];
  int t = blockIdx.x, tid = threadIdx.x;
  for (int i = tid; i < Bn*Un; i += 256) hl[i] = h_all[(size_t)t*Bn*Un + i];
  __syncthreads();
  int j = tid;
  float bj = b1[j];
  float acc[32];
  #pragma unroll
  for (int r = 0; r < 32; ++r) acc[r] = bj;
  for (int u = 0; u < Un; ++u){
    float wv = W1[u*Un + j];
    #pragma unroll
    for (int r = 0; r < 32; ++r) acc[r] += hl[r*Un + u]*wv;
  }
  #pragma unroll
  for (int r = 0; r < 32; ++r) hid[(size_t)(t*Bn + r)*Un + j] = f2bf(acc[r]);
}

// pg[t] via row-0 quirk
__global__ __launch_bounds__(256) void k_pg(const float* __restrict__ a_all,
    const float* __restrict__ enc_out, const float* __restrict__ h_all,
    const float* __restrict__ c0_all, const float* __restrict__ gpWs,
    const float* __restrict__ gpWc, const float* __restrict__ gpx,
    const float* __restrict__ gpWg, float* __restrict__ pg){
  __shared__ float al[Sn];
  __shared__ float cv[ENCn];
  __shared__ float red[4];
  int t = blockIdx.x, tid = threadIdx.x;
  for (int s = tid; s < Sn; s += 256) al[s] = a_all[(size_t)(t*Bn + 0)*Sn + s];
  __syncthreads();
  for (int e = tid; e < ENCn; e += 256){
    float acc = 0.f;
    for (int s = 0; s < Sn; ++s) acc += enc_out[(size_t)s*ENCn + e]*al[s];
    cv[e] = acc;
  }
  __syncthreads();
  int j = tid;
  float g = gpx[t*GPn + j];
  const float* h0r = h_all + (size_t)t*Bn*Un;       // b = 0 row
  const float* c0r = c0_all + t*Un;
  for (int u = 0; u < Un; ++u) g += h0r[u]*gpWs[u*GPn + j];
  for (int u = 0; u < Un; ++u) g += c0r[u]*gpWs[(Un+u)*GPn + j];
  for (int e = 0; e < ENCn; ++e) g += cv[e]*gpWc[e*GPn + j];
  float v = g * gpWg[j];
  int lane = tid & 63, wv2 = tid >> 6;
  #pragma unroll
  for (int m = 1; m < 64; m <<= 1) v += __shfl_xor(v, m);
  if (lane == 0) red[wv2] = v;
  __syncthreads();
  if (tid == 0) pg[t] = 1.f/(1.f+__expf(-(red[0]+red[1]+red[2]+red[3])));
}

// GEMM: A = hid [3200][256] bf16, B = W2T [32000][256] bf16.
// mode 0: Ssum[r] += sum_v exp(logit);  mode 1: probs = pg*exp/S (+OOV zeros) + amax
__global__ __launch_bounds__(256) void k_gemm(const ushort_t* __restrict__ A,
    const ushort_t* __restrict__ Bw, const float* __restrict__ b2,
    float* __restrict__ Ssum, u64* __restrict__ amax, const float* __restrict__ pg,
    float* __restrict__ probs, int mode){
  int r0 = blockIdx.x * 64;
  int n0 = blockIdx.y * 256;
  int tid = threadIdx.x;
  if (mode == 1 && n0 >= Vn){
    for (int idx = tid; idx < 64*OOVn; idx += 256){
      int i = idx/OOVn, vv = idx%OOVn;
      int r = r0+i; int tt = r>>5, bb = r&31;
      probs[(size_t)(bb*Tn+tt)*VEn + Vn + vv] = 0.f;
    }
    return;
  }
  __shared__ ushort_t Bs[64*264];          // [64 n][256 k + pad8]
  int lane = tid & 63, w = tid >> 6;
  bf16x8 af[8];
  {
    const ushort_t* ar = A + (size_t)(r0 + w*16 + (lane&15))*Un + (lane>>4)*8;
    #pragma unroll
    for (int kk = 0; kk < 8; ++kk) af[kk] = *(const bf16x8*)(ar + kk*32);
  }
  f32x4 acc[16];
  #pragma unroll
  for (int i = 0; i < 16; ++i) acc[i] = (f32x4){0.f,0.f,0.f,0.f};

  for (int nsub = 0; nsub < 4; ++nsub){
    __syncthreads();
    {
      const ushort_t* gb = Bw + (size_t)(n0 + nsub*64)*Un;
      #pragma unroll
      for (int i = 0; i < 8; ++i){
        int chunk = tid + i*256;
        int rr = chunk >> 5, cc = chunk & 31;
        uint4 d = *(const uint4*)(gb + rr*Un + cc*8);
        *(uint4*)(Bs + rr*264 + cc*8) = d;
      }
    }
    __syncthreads();
    #pragma unroll
    for (int kk = 0; kk < 8; ++kk){
      #pragma unroll
      for (int ntl = 0; ntl < 4; ++ntl){
        bf16x8 bf = *(const bf16x8*)(Bs + (ntl*16 + (lane&15))*264 + kk*32 + (lane>>4)*8);
        acc[nsub*4+ntl] = __builtin_amdgcn_mfma_f32_16x16x32_bf16(af[kk], bf, acc[nsub*4+ntl], 0, 0, 0);
      }
    }
  }

  int rowloc = w*16 + (lane>>4)*4;
  if (mode == 0){
    float rs[4] = {0.f,0.f,0.f,0.f};
    #pragma unroll
    for (int nt = 0; nt < 16; ++nt){
      int v = n0 + (nt>>2)*64 + (nt&3)*16 + (lane&15);
      float bb = b2[v];
      #pragma unroll
      for (int i = 0; i < 4; ++i) rs[i] += __expf(acc[nt][i] + bb);
    }
    #pragma unroll
    for (int m = 1; m < 16; m <<= 1)
      #pragma unroll
      for (int i = 0; i < 4; ++i) rs[i] += __shfl_xor(rs[i], m);
    if ((lane&15) == 0)
      #pragma unroll
      for (int i = 0; i < 4; ++i) atomicAdd(&Ssum[r0+rowloc+i], rs[i]);
  } else {
    float sc[4]; size_t obase[4];
    #pragma unroll
    for (int i = 0; i < 4; ++i){
      int r = r0+rowloc+i; int tt = r>>5, bb = r&31;
      sc[i] = pg[tt] / Ssum[r];
      obase[i] = (size_t)(bb*Tn+tt)*VEn;
    }
    u64 pm[4] = {0,0,0,0};
    #pragma unroll
    for (int nt = 0; nt < 16; ++nt){
      int v = n0 + (nt>>2)*64 + (nt&3)*16 + (lane&15);
      float bb = b2[v];
      #pragma unroll
      for (int i = 0; i < 4; ++i){
        float val = __expf(acc[nt][i] + bb) * sc[i];
        probs[obase[i] + v] = val;
        u64 p = ((u64)__float_as_uint(val)<<32) | (u64)(0xFFFFFFFFu - (unsigned)v);
        pm[i] = p > pm[i] ? p : pm[i];
      }
    }
    #pragma unroll
    for (int m = 1; m < 16; m <<= 1)
      #pragma unroll
      for (int i = 0; i < 4; ++i){
        u64 o = shfl_xor_u64(pm[i], m);
        pm[i] = o > pm[i] ? o : pm[i];
      }
    if ((lane&15) == 0)
      #pragma unroll
      for (int i = 0; i < 4; ++i) atomicMax(&amax[r0+rowloc+i], pm[i]);
  }
}

// scatter copy-dist into probs (deduped single-writer) + update amax
__global__ __launch_bounds__(256) void k_scatter(const int* __restrict__ ext,
    const float* __restrict__ a_all, const float* __restrict__ pg,
    float* __restrict__ probs, u64* __restrict__ amax){
  __shared__ int tok[Sn];
  __shared__ float val[Sn];
  int r = blockIdx.x; int t = r>>5, b = r&31;
  float c1 = 1.f - pg[t];
  int tid = threadIdx.x;
  for (int s = tid; s < Sn; s += 256){
    tok[s] = ext[b*Sn + s];
    val[s] = c1 * a_all[(size_t)r*Sn + s];
  }
  __syncthreads();
  size_t obase = (size_t)(b*Tn + t)*VEn;
  for (int s = tid; s < Sn; s += 256){
    int tk = tok[s];
    bool leader = true;
    float tot = 0.f;
    for (int s2 = 0; s2 < Sn; ++s2){
      if (tok[s2] == tk){
        if (s2 < s){ leader = false; break; }
        tot += val[s2];
      }
    }
    if (leader){
      float nv = probs[obase + tk] + tot;
      probs[obase + tk] = nv;
      u64 p = ((u64)__float_as_uint(nv)<<32) | (u64)(0xFFFFFFFFu - (unsigned)tk);
      atomicMax(&amax[r], p);
    }
  }
}

__global__ __launch_bounds__(256) void k_seqout(const u64* __restrict__ amax,
    float* __restrict__ seqs){
  int r = blockIdx.x*256 + threadIdx.x;
  if (r >= Tn*Bn) return;
  int t = r>>5, b = r&31;
  unsigned tk = 0xFFFFFFFFu - (unsigned)(amax[r] & 0xFFFFFFFFull);
  seqs[b*Tn + t] = (float)tk;
}

// ---------------- host launch ----------------

extern "C" void kernel_launch(void* const* d_in, const int* in_sizes, int n_in,
                              void* d_out, int out_size, void* d_ws, size_t ws_size,
                              hipStream_t stream){
  (void)in_sizes; (void)n_in; (void)out_size; (void)ws_size;
  const int*   gt       = (const int*)d_in[0];
  const int*   ext      = (const int*)d_in[1];
  const float* enc_out  = (const float*)d_in[2];
  const float* enc_attn = (const float*)d_in[3];
  const float* h0       = (const float*)d_in[4];
  const float* c0       = (const float*)d_in[5];
  const float* emb      = (const float*)d_in[6];
  const float* Wk       = (const float*)d_in[7];
  const float* Wr       = (const float*)d_in[8];
  const float* lb       = (const float*)d_in[9];
  const float* Wd       = (const float*)d_in[10];
  const float* bd       = (const float*)d_in[11];
  const float* Wc       = (const float*)d_in[12];
  const float* Wa       = (const float*)d_in[13];
  const float* W1       = (const float*)d_in[14];
  const float* b1       = (const float*)d_in[15];
  const float* W2       = (const float*)d_in[16];
  const float* b2       = (const float*)d_in[17];
  const float* gpWs     = (const float*)d_in[18];
  const float* gpWc     = (const float*)d_in[19];
  const float* gpWi     = (const float*)d_in[20];
  const float* gpbi     = (const float*)d_in[21];
  const float* gpWg     = (const float*)d_in[22];

  float* probs   = (float*)d_out;
  float* seqs    = probs + (size_t)Bn*Tn*VEn;
  float* covloss = seqs + Bn*Tn;

  char* wp = (char*)d_ws;
  auto carve = [&](size_t bytes)->void*{
    void* p = (void*)wp; wp += (bytes + 255) & ~(size_t)255; return p;
  };
  float*    Xall    = (float*)carve((size_t)3200*En*4);
  float*    Zx      = (float*)carve((size_t)3200*Z4n*4);
  float*    gpx     = (float*)carve((size_t)Tn*GPn*4);
  float*    h_all   = (float*)carve((size_t)Tn*Bn*Un*4);
  float*    decp    = (float*)carve((size_t)Bn*8*256*4);
  float*    c0_all  = (float*)carve((size_t)Tn*Un*4);
  float*    a_all   = (float*)carve((size_t)3200*Sn*4);
  ushort_t* hid_bf  = (ushort_t*)carve((size_t)3200*Un*2);
  ushort_t* W2T     = (ushort_t*)carve((size_t)Vn*Un*2);
  float*    Ssum    = (float*)carve((size_t)3200*4);
  u64*      amax    = (u64*)carve((size_t)3200*8);
  float*    pg      = (float*)carve((size_t)Tn*4);
  float*    psum    = (float*)carve((size_t)Bn*8*4);
  unsigned* bars    = (unsigned*)carve((size_t)Bn*8*32*4);

  hipMemsetAsync(Ssum, 0, 3200*4, stream);
  hipMemsetAsync(amax, 0, 3200*8, stream);
  hipMemsetAsync(bars, 0, Bn*8*32*4, stream);
  hipMemsetAsync(covloss, 0, Bn*Tn*4, stream);

  k_gather<<<3200, 256, 0, stream>>>(gt, emb, Xall);
  k_zx    <<<dim3(50,16), 256, 0, stream>>>(Xall, Wk, lb, Zx);
  k_gpx   <<<Tn, 256, 0, stream>>>(Xall, gpWi, gpbi, gpx);
  k_w2t   <<<dim3(500,4), 256, 0, stream>>>(W2, W2T);

  k_loop  <<<256, 1024, 0, stream>>>(Zx, Wr, Wd, bd, Wc, Wa, enc_attn,
                                     h0, c0, h_all, decp, c0_all,
                                     a_all, covloss, psum, bars);

  k_hid <<<Tn, 256, 0, stream>>>(h_all, W1, b1, hid_bf);
  k_pg  <<<Tn, 256, 0, stream>>>(a_all, enc_out, h_all, c0_all, gpWs, gpWc, gpx, gpWg, pg);
  k_gemm<<<dim3(50,125), 256, 0, stream>>>(hid_bf, W2T, b2, Ssum, amax, pg, probs, 0);
  k_gemm<<<dim3(50,126), 256, 0, stream>>>(hid_bf, W2T, b2, Ssum, amax, pg, probs, 1);
  k_scatter<<<3200, 256, 0, stream>>>(ext, a_all, pg, probs, amax);
  k_seqout <<<13, 256, 0, stream>>>(amax, seqs);
}

// Round 5
// 1512.459 us; speedup vs baseline: 3.4963x; 1.7568x over previous
//
#include <hip/hip_runtime.h>
#include <hip/hip_bf16.h>

#define Bn 32
#define Sn 400
#define Tn 100
#define Vn 32000
#define OOVn 100
#define VEn 32100
#define En 512
#define Un 256
#define AUn 256
#define GPn 256
#define ENCn 512
#define Z4n 1024

typedef __attribute__((ext_vector_type(8))) short bf16x8;
typedef __attribute__((ext_vector_type(4))) float f32x4;
typedef unsigned short ushort_t;
typedef unsigned long long u64;

__device__ __forceinline__ float rcp_f(float x){ return __builtin_amdgcn_rcpf(x); }
__device__ __forceinline__ float tanh_fast(float x){
  float e2 = __expf(2.f*x);
  return 1.f - 2.f*rcp_f(e2 + 1.f);
}
__device__ __forceinline__ float sigmoid_f(float x){ return 1.f/(1.f+__expf(-x)); }
__device__ __forceinline__ ushort_t f2bf(float f){
  unsigned u = __float_as_uint(f);
  unsigned r = (u + 0x7FFFu + ((u>>16)&1u)) >> 16;   // RNE
  return (ushort_t)r;
}
__device__ __forceinline__ u64 shfl_xor_u64(u64 v, int m){
  unsigned lo = (unsigned)v, hi = (unsigned)(v>>32);
  lo = (unsigned)__shfl_xor((int)lo, m);
  hi = (unsigned)__shfl_xor((int)hi, m);
  return ((u64)hi<<32)|(u64)lo;
}

// relaxed agent-scope data movement: L1/L2-bypassing (coherence-point) ops,
// no wbl2/invl2 cache maintenance. Ordering via __syncthreads vmcnt drain.
__device__ __forceinline__ void st_rlx(float* p, float v){
  __hip_atomic_store(p, v, __ATOMIC_RELAXED, __HIP_MEMORY_SCOPE_AGENT);
}
__device__ __forceinline__ float ld_rlx(const float* p){
  return __hip_atomic_load(p, __ATOMIC_RELAXED, __HIP_MEMORY_SCOPE_AGENT);
}

// ---------------- pre-loop kernels ----------------

__global__ __launch_bounds__(256) void k_gather(const int* __restrict__ gt,
    const float* __restrict__ emb, float* __restrict__ Xall){
  int r = blockIdx.x;                 // r = t*32 + b
  int t = r >> 5, b = r & 31;
  int tok = gt[b*Tn + t];
  const float* src = emb + (size_t)tok*En;
  float* dst = Xall + (size_t)r*En;
  for (int i = threadIdx.x; i < En; i += 256) dst[i] = src[i];
}

// Zx = Xall @ Wk + bias   [3200,512]@[512,1024], f32 tiled 64x64
__global__ __launch_bounds__(256) void k_zx(const float* __restrict__ X,
    const float* __restrict__ Wk, const float* __restrict__ bias, float* __restrict__ Zx){
  __shared__ float As[64][17];
  __shared__ float Bs[16][65];
  int r0 = blockIdx.x * 64;
  int c0 = blockIdx.y * 64;
  int tid = threadIdx.x;
  int ty = tid >> 4, tx = tid & 15;
  float acc[4][4] = {};
  for (int k0 = 0; k0 < En; k0 += 16){
    #pragma unroll
    for (int p = 0; p < 4; ++p){
      int row = (tid>>4) + p*16, kk = tid & 15;
      As[row][kk] = X[(size_t)(r0+row)*En + k0 + kk];
    }
    #pragma unroll
    for (int p = 0; p < 4; ++p){
      int kk = (tid>>6) + p*4, cc = tid & 63;
      Bs[kk][cc] = Wk[(size_t)(k0+kk)*Z4n + c0 + cc];
    }
    __syncthreads();
    #pragma unroll
    for (int kk = 0; kk < 16; ++kk){
      float av[4], bv[4];
      #pragma unroll
      for (int i=0;i<4;++i) av[i] = As[ty*4+i][kk];
      #pragma unroll
      for (int j=0;j<4;++j) bv[j] = Bs[kk][tx*4+j];
      #pragma unroll
      for (int i=0;i<4;++i)
        #pragma unroll
        for (int j=0;j<4;++j) acc[i][j] += av[i]*bv[j];
    }
    __syncthreads();
  }
  #pragma unroll
  for (int i=0;i<4;++i){
    int row = r0 + ty*4 + i;
    #pragma unroll
    for (int j=0;j<4;++j){
      int col = c0 + tx*4 + j;
      Zx[(size_t)row*Z4n + col] = acc[i][j] + bias[col];
    }
  }
}

// gpx[t,:] = x[t,b=0,:] @ gp_Wi + gp_bi
__global__ __launch_bounds__(256) void k_gpx(const float* __restrict__ Xall,
    const float* __restrict__ Wi, const float* __restrict__ bi, float* __restrict__ gpx){
  int t = blockIdx.x, j = threadIdx.x;
  const float* x = Xall + (size_t)(t*Bn + 0)*En;
  float acc = bi[j];
  for (int u = 0; u < En; ++u) acc += x[u]*Wi[u*GPn + j];
  gpx[t*GPn + j] = acc;
}

// W2 [256][32000] f32 -> W2T [32000][256] bf16 (LDS-tiled transpose)
__global__ __launch_bounds__(256) void k_w2t(const float* __restrict__ W2,
    ushort_t* __restrict__ W2T){
  __shared__ float tile[64][65];
  int n0 = blockIdx.x * 64;   // 500
  int k0 = blockIdx.y * 64;   // 4
  int tx = threadIdx.x & 63, ty4 = threadIdx.x >> 6;
  #pragma unroll
  for (int i = 0; i < 16; ++i){
    int k = ty4 + i*4;
    tile[k][tx] = W2[(size_t)(k0+k)*Vn + n0 + tx];
  }
  __syncthreads();
  #pragma unroll
  for (int i = 0; i < 16; ++i){
    int n = ty4 + i*4;
    W2T[(size_t)(n0+n)*Un + k0 + tx] = f2bf(tile[tx][n]);
  }
}

// ---------------- persistent 256-block recurrent kernel ----------------
// b = blockIdx&31, k = blockIdx>>5. Block k of group b owns:
//   LSTM h-cols [32k,32k+32) (Wr slice LDS-resident), dec-attn PARTIAL over
//   its own h/c rows, attention s-rows [50k,50k+50).
// All cross-block data via relaxed agent-scope atomics (coherence-point ops,
// no cache flushes). 2 flag barriers/step; ordering via vmcnt drains.

__global__ __launch_bounds__(1024, 1) void k_loop(
    const float* __restrict__ Zx, const float* __restrict__ Wr,
    const float* __restrict__ Wd, const float* __restrict__ bd,
    const float* __restrict__ Wc, const float* __restrict__ Wa,
    const float* __restrict__ enc_attn,
    const float* __restrict__ h0, const float* __restrict__ c0,
    float* __restrict__ h_all, float* __restrict__ decp,
    float* __restrict__ c0_all, float* __restrict__ a_all,
    float* __restrict__ covloss, float* __restrict__ psum,
    unsigned* __restrict__ bars){
  __shared__ float Wr_lds[256*128];     // 128 KB: Wr cols {32k+i+256q}
  __shared__ float hprev[Un];
  __shared__ float ppart[8][132];
  __shared__ float zfull[128];
  __shared__ float hnew[32], cown[32];
  __shared__ float ppB[4][260];
  __shared__ float dec_lds[AUn];
  __shared__ float cov_lds[64], sc_lds[64];
  __shared__ float wred[16];
  __shared__ float psred[8];

  const int b = blockIdx.x & 31, k = blockIdx.x >> 5;
  const int tid = threadIdx.x, lane = tid & 63, w = tid >> 6;
  unsigned* flags = bars + b*8*32;          // 8 slots, 128 B apart
  unsigned* myflag = flags + k*32;

  for (int idx = tid; idx < 256*128; idx += 1024){
    int u = idx >> 7, jl = idx & 127;
    int gcol = 32*k + (jl & 31) + 256*(jl >> 5);
    Wr_lds[idx] = Wr[(size_t)u*Z4n + gcol];
  }
  if (tid < 32) cown[tid] = c0[b*Un + 32*k + tid];
  if (tid < 50) cov_lds[tid] = 0.f;
  const float4 wc4 = *(const float4*)(Wc + lane*4);
  const float4 wa4 = *(const float4*)(Wa + lane*4);
  __syncthreads();

  for (int t = 0; t < Tn; ++t){
    // ======== phase A: LSTM slice + dec partials ========
    if (tid < Un){
      hprev[tid] = (t == 0) ? h0[b*Un + tid]
                            : ld_rlx(h_all + (size_t)((t-1)*Bn + b)*Un + tid);
    }
    __syncthreads();
    {
      int jl = tid & 127, p = tid >> 7;
      float acc = 0.f;
      const float* wr = Wr_lds + (p*32)*128 + jl;
      const float* hb = hprev + p*32;
      #pragma unroll 8
      for (int uu = 0; uu < 32; ++uu) acc += hb[uu] * wr[uu*128];
      ppart[p][jl] = acc;
    }
    __syncthreads();
    if (tid < 128){
      float s = 0.f;
      #pragma unroll
      for (int q = 0; q < 8; ++q) s += ppart[q][tid];
      int gcol = 32*k + (tid & 31) + 256*(tid >> 5);
      zfull[tid] = s + Zx[(size_t)(t*Bn + b)*Z4n + gcol];
    }
    __syncthreads();
    if (tid < 32){
      float zi = zfull[tid], zf = zfull[32+tid], zg = zfull[64+tid], zo = zfull[96+tid];
      float cn = sigmoid_f(zf)*cown[tid] + sigmoid_f(zi)*tanhf(zg);
      float hn = sigmoid_f(zo)*tanhf(cn);
      cown[tid] = cn; hnew[tid] = hn;
      int col = 32*k + tid;
      st_rlx(h_all + (size_t)(t*Bn + b)*Un + col, hn);
      if (b == 0) c0_all[t*Un + col] = cn;
    }
    __syncthreads();
    {   // dec partial over own 64 rows (32 h + 32 c)
      int j = tid & 255, p = tid >> 8;
      int r0 = (p & 1)*16;
      const float* sb = ((p < 2) ? hnew : cown) + r0;
      int urow = (p < 2) ? (32*k + r0) : (Un + 32*k + r0);
      const float* wd = Wd + (size_t)urow*AUn + j;
      float acc = 0.f;
      #pragma unroll
      for (int uu = 0; uu < 16; ++uu) acc += sb[uu] * wd[(size_t)uu*AUn];
      ppB[p][j] = acc;
    }
    __syncthreads();
    if (tid < 256)
      st_rlx(decp + (size_t)(b*8 + k)*256 + tid,
             ppB[0][tid]+ppB[1][tid]+ppB[2][tid]+ppB[3][tid]);
    // ---- barrier 1 (publishes h_all slice + decp) ----
    {
      unsigned p1 = 2*(unsigned)t + 1;
      __syncthreads();   // drains vmcnt: data stores acknowledged before flag
      if (tid == 0)
        __hip_atomic_store(myflag, p1, __ATOMIC_RELAXED, __HIP_MEMORY_SCOPE_AGENT);
      if (tid < 8){
        while (__hip_atomic_load(flags + tid*32, __ATOMIC_RELAXED,
                                 __HIP_MEMORY_SCOPE_AGENT) < p1)
          __builtin_amdgcn_s_sleep(1);
      }
      __syncthreads();
    }
    // ======== phase C: dec sum + scores + exp-partials ========
    if (tid < 256){
      float s = bd[tid];
      const float* dp = decp + (size_t)b*8*256 + tid;
      #pragma unroll
      for (int q = 0; q < 8; ++q) s += ld_rlx(dp + q*256);
      dec_lds[tid] = s;
    }
    __syncthreads();
    {
      const float4 da = *(const float4*)(dec_lds + lane*4);
      float wsum = 0.f;
      for (int sl = w; sl < 50; sl += 16){
        int s = 50*k + sl;
        float cvv = cov_lds[sl];
        const float4 e = *(const float4*)(enc_attn + ((size_t)(b*Sn + s))*AUn + lane*4);
        float psc = tanh_fast(e.x + cvv*wc4.x + da.x)*wa4.x
                  + tanh_fast(e.y + cvv*wc4.y + da.y)*wa4.y
                  + tanh_fast(e.z + cvv*wc4.z + da.z)*wa4.z
                  + tanh_fast(e.w + cvv*wc4.w + da.w)*wa4.w;
        #pragma unroll
        for (int m = 1; m < 64; m <<= 1) psc += __shfl_xor(psc, m);
        if (lane == 0){
          float ev = __expf(psc);
          sc_lds[sl] = ev;
          wsum += ev;
        }
      }
      if (lane == 0) wred[w] = wsum;
    }
    __syncthreads();
    if (tid == 0){
      float S = 0.f;
      #pragma unroll
      for (int q = 0; q < 16; ++q) S += wred[q];
      st_rlx(psum + b*8 + k, S);
    }
    // ---- barrier 2 (publishes psum) ----
    {
      unsigned p2 = 2*(unsigned)t + 2;
      __syncthreads();
      if (tid == 0)
        __hip_atomic_store(myflag, p2, __ATOMIC_RELAXED, __HIP_MEMORY_SCOPE_AGENT);
      if (tid < 8){
        while (__hip_atomic_load(flags + tid*32, __ATOMIC_RELAXED,
                                 __HIP_MEMORY_SCOPE_AGENT) < p2)
          __builtin_amdgcn_s_sleep(1);
      }
      __syncthreads();
    }
    // ======== phase D: normalize + cov update (no trailing barrier) ========
    if (tid < 8) psred[tid] = ld_rlx(psum + b*8 + tid);
    __syncthreads();
    if (tid < 64){
      float S = psred[0]+psred[1]+psred[2]+psred[3]+psred[4]+psred[5]+psred[6]+psred[7];
      float inv = 1.f / S;
      float clp = 0.f;
      if (tid < 50){
        float aa = sc_lds[tid] * inv;
        float co = cov_lds[tid];
        a_all[(size_t)(t*Bn + b)*Sn + 50*k + tid] = aa;
        clp = fminf(co, aa);
        cov_lds[tid] = co + aa;
      }
      #pragma unroll
      for (int m = 1; m < 64; m <<= 1) clp += __shfl_xor(clp, m);
      if (tid == 0) atomicAdd(&covloss[b*Tn + t], clp);
    }
    // next overwrites of decp/psum sit behind the next step's barriers
  }
}

// ---------------- post-loop kernels ----------------

// hid = h_all @ W1 + b1 -> bf16    (block per t)
__global__ __launch_bounds__(256) void k_hid(const float* __restrict__ h_all,
    const float* __restrict__ W1, const float* __restrict__ b1, ushort_t* __restrict__ hid){
  __shared__ float hl[Bn*Un];
  int t = blockIdx.x, tid = threadIdx.x;
  for (int i = tid; i < Bn*Un; i += 256) hl[i] = h_all[(size_t)t*Bn*Un + i];
  __syncthreads();
  int j = tid;
  float bj = b1[j];
  float acc[32];
  #pragma unroll
  for (int r = 0; r < 32; ++r) acc[r] = bj;
  for (int u = 0; u < Un; ++u){
    float wv = W1[u*Un + j];
    #pragma unroll
    for (int r = 0; r < 32; ++r) acc[r] += hl[r*Un + u]*wv;
  }
  #pragma unroll
  for (int r = 0; r < 32; ++r) hid[(size_t)(t*Bn + r)*Un + j] = f2bf(acc[r]);
}

// pg[t] via row-0 quirk
__global__ __launch_bounds__(256) void k_pg(const float* __restrict__ a_all,
    const float* __restrict__ enc_out, const float* __restrict__ h_all,
    const float* __restrict__ c0_all, const float* __restrict__ gpWs,
    const float* __restrict__ gpWc, const float* __restrict__ gpx,
    const float* __restrict__ gpWg, float* __restrict__ pg){
  __shared__ float al[Sn];
  __shared__ float cv[ENCn];
  __shared__ float red[4];
  int t = blockIdx.x, tid = threadIdx.x;
  for (int s = tid; s < Sn; s += 256) al[s] = a_all[(size_t)(t*Bn + 0)*Sn + s];
  __syncthreads();
  for (int e = tid; e < ENCn; e += 256){
    float acc = 0.f;
    for (int s = 0; s < Sn; ++s) acc += enc_out[(size_t)s*ENCn + e]*al[s];
    cv[e] = acc;
  }
  __syncthreads();
  int j = tid;
  float g = gpx[t*GPn + j];
  const float* h0r = h_all + (size_t)t*Bn*Un;       // b = 0 row
  const float* c0r = c0_all + t*Un;
  for (int u = 0; u < Un; ++u) g += h0r[u]*gpWs[u*GPn + j];
  for (int u = 0; u < Un; ++u) g += c0r[u]*gpWs[(Un+u)*GPn + j];
  for (int e = 0; e < ENCn; ++e) g += cv[e]*gpWc[e*GPn + j];
  float v = g * gpWg[j];
  int lane = tid & 63, wv2 = tid >> 6;
  #pragma unroll
  for (int m = 1; m < 64; m <<= 1) v += __shfl_xor(v, m);
  if (lane == 0) red[wv2] = v;
  __syncthreads();
  if (tid == 0) pg[t] = 1.f/(1.f+__expf(-(red[0]+red[1]+red[2]+red[3])));
}

// GEMM: A = hid [3200][256] bf16, B = W2T [32000][256] bf16.
// mode 0: Ssum[r] += sum_v exp(logit);  mode 1: probs = pg*exp/S (+OOV zeros) + amax
__global__ __launch_bounds__(256) void k_gemm(const ushort_t* __restrict__ A,
    const ushort_t* __restrict__ Bw, const float* __restrict__ b2,
    float* __restrict__ Ssum, u64* __restrict__ amax, const float* __restrict__ pg,
    float* __restrict__ probs, int mode){
  int r0 = blockIdx.x * 64;
  int n0 = blockIdx.y * 256;
  int tid = threadIdx.x;
  if (mode == 1 && n0 >= Vn){
    for (int idx = tid; idx < 64*OOVn; idx += 256){
      int i = idx/OOVn, vv = idx%OOVn;
      int r = r0+i; int tt = r>>5, bb = r&31;
      probs[(size_t)(bb*Tn+tt)*VEn + Vn + vv] = 0.f;
    }
    return;
  }
  __shared__ ushort_t Bs[64*264];          // [64 n][256 k + pad8]
  int lane = tid & 63, w = tid >> 6;
  bf16x8 af[8];
  {
    const ushort_t* ar = A + (size_t)(r0 + w*16 + (lane&15))*Un + (lane>>4)*8;
    #pragma unroll
    for (int kk = 0; kk < 8; ++kk) af[kk] = *(const bf16x8*)(ar + kk*32);
  }
  f32x4 acc[16];
  #pragma unroll
  for (int i = 0; i < 16; ++i) acc[i] = (f32x4){0.f,0.f,0.f,0.f};

  for (int nsub = 0; nsub < 4; ++nsub){
    __syncthreads();
    {
      const ushort_t* gb = Bw + (size_t)(n0 + nsub*64)*Un;
      #pragma unroll
      for (int i = 0; i < 8; ++i){
        int chunk = tid + i*256;
        int rr = chunk >> 5, cc = chunk & 31;
        uint4 d = *(const uint4*)(gb + rr*Un + cc*8);
        *(uint4*)(Bs + rr*264 + cc*8) = d;
      }
    }
    __syncthreads();
    #pragma unroll
    for (int kk = 0; kk < 8; ++kk){
      #pragma unroll
      for (int ntl = 0; ntl < 4; ++ntl){
        bf16x8 bf = *(const bf16x8*)(Bs + (ntl*16 + (lane&15))*264 + kk*32 + (lane>>4)*8);
        acc[nsub*4+ntl] = __builtin_amdgcn_mfma_f32_16x16x32_bf16(af[kk], bf, acc[nsub*4+ntl], 0, 0, 0);
      }
    }
  }

  int rowloc = w*16 + (lane>>4)*4;
  if (mode == 0){
    float rs[4] = {0.f,0.f,0.f,0.f};
    #pragma unroll
    for (int nt = 0; nt < 16; ++nt){
      int v = n0 + (nt>>2)*64 + (nt&3)*16 + (lane&15);
      float bb = b2[v];
      #pragma unroll
      for (int i = 0; i < 4; ++i) rs[i] += __expf(acc[nt][i] + bb);
    }
    #pragma unroll
    for (int m = 1; m < 16; m <<= 1)
      #pragma unroll
      for (int i = 0; i < 4; ++i) rs[i] += __shfl_xor(rs[i], m);
    if ((lane&15) == 0)
      #pragma unroll
      for (int i = 0; i < 4; ++i) atomicAdd(&Ssum[r0+rowloc+i], rs[i]);
  } else {
    float sc[4]; size_t obase[4];
    #pragma unroll
    for (int i = 0; i < 4; ++i){
      int r = r0+rowloc+i; int tt = r>>5, bb = r&31;
      sc[i] = pg[tt] / Ssum[r];
      obase[i] = (size_t)(bb*Tn+tt)*VEn;
    }
    u64 pm[4] = {0,0,0,0};
    #pragma unroll
    for (int nt = 0; nt < 16; ++nt){
      int v = n0 + (nt>>2)*64 + (nt&3)*16 + (lane&15);
      float bb = b2[v];
      #pragma unroll
      for (int i = 0; i < 4; ++i){
        float val = __expf(acc[nt][i] + bb) * sc[i];
        probs[obase[i] + v] = val;
        u64 p = ((u64)__float_as_uint(val)<<32) | (u64)(0xFFFFFFFFu - (unsigned)v);
        pm[i] = p > pm[i] ? p : pm[i];
      }
    }
    #pragma unroll
    for (int m = 1; m < 16; m <<= 1)
      #pragma unroll
      for (int i = 0; i < 4; ++i){
        u64 o = shfl_xor_u64(pm[i], m);
        pm[i] = o > pm[i] ? o : pm[i];
      }
    if ((lane&15) == 0)
      #pragma unroll
      for (int i = 0; i < 4; ++i) atomicMax(&amax[r0+rowloc+i], pm[i]);
  }
}

// scatter copy-dist into probs (deduped single-writer) + update amax
__global__ __launch_bounds__(256) void k_scatter(const int* __restrict__ ext,
    const float* __restrict__ a_all, const float* __restrict__ pg,
    float* __restrict__ probs, u64* __restrict__ amax){
  __shared__ int tok[Sn];
  __shared__ float val[Sn];
  int r = blockIdx.x; int t = r>>5, b = r&31;
  float c1 = 1.f - pg[t];
  int tid = threadIdx.x;
  for (int s = tid; s < Sn; s += 256){
    tok[s] = ext[b*Sn + s];
    val[s] = c1 * a_all[(size_t)r*Sn + s];
  }
  __syncthreads();
  size_t obase = (size_t)(b*Tn + t)*VEn;
  for (int s = tid; s < Sn; s += 256){
    int tk = tok[s];
    bool leader = true;
    float tot = 0.f;
    for (int s2 = 0; s2 < Sn; ++s2){
      if (tok[s2] == tk){
        if (s2 < s){ leader = false; break; }
        tot += val[s2];
      }
    }
    if (leader){
      float nv = probs[obase + tk] + tot;
      probs[obase + tk] = nv;
      u64 p = ((u64)__float_as_uint(nv)<<32) | (u64)(0xFFFFFFFFu - (unsigned)tk);
      atomicMax(&amax[r], p);
    }
  }
}

__global__ __launch_bounds__(256) void k_seqout(const u64* __restrict__ amax,
    float* __restrict__ seqs){
  int r = blockIdx.x*256 + threadIdx.x;
  if (r >= Tn*Bn) return;
  int t = r>>5, b = r&31;
  unsigned tk = 0xFFFFFFFFu - (unsigned)(amax[r] & 0xFFFFFFFFull);
  seqs[b*Tn + t] = (float)tk;
}

// ---------------- host launch ----------------

extern "C" void kernel_launch(void* const* d_in, const int* in_sizes, int n_in,
                              void* d_out, int out_size, void* d_ws, size_t ws_size,
                              hipStream_t stream){
  (void)in_sizes; (void)n_in; (void)out_size; (void)ws_size;
  const int*   gt       = (const int*)d_in[0];
  const int*   ext      = (const int*)d_in[1];
  const float* enc_out  = (const float*)d_in[2];
  const float* enc_attn = (const float*)d_in[3];
  const float* h0       = (const float*)d_in[4];
  const float* c0       = (const float*)d_in[5];
  const float* emb      = (const float*)d_in[6];
  const float* Wk       = (const float*)d_in[7];
  const float* Wr       = (const float*)d_in[8];
  const float* lb       = (const float*)d_in[9];
  const float* Wd       = (const float*)d_in[10];
  const float* bd       = (const float*)d_in[11];
  const float* Wc       = (const float*)d_in[12];
  const float* Wa       = (const float*)d_in[13];
  const float* W1       = (const float*)d_in[14];
  const float* b1       = (const float*)d_in[15];
  const float* W2       = (const float*)d_in[16];
  const float* b2       = (const float*)d_in[17];
  const float* gpWs     = (const float*)d_in[18];
  const float* gpWc     = (const float*)d_in[19];
  const float* gpWi     = (const float*)d_in[20];
  const float* gpbi     = (const float*)d_in[21];
  const float* gpWg     = (const float*)d_in[22];

  float* probs   = (float*)d_out;
  float* seqs    = probs + (size_t)Bn*Tn*VEn;
  float* covloss = seqs + Bn*Tn;

  char* wp = (char*)d_ws;
  auto carve = [&](size_t bytes)->void*{
    void* p = (void*)wp; wp += (bytes + 255) & ~(size_t)255; return p;
  };
  float*    Xall    = (float*)carve((size_t)3200*En*4);
  float*    Zx      = (float*)carve((size_t)3200*Z4n*4);
  float*    gpx     = (float*)carve((size_t)Tn*GPn*4);
  float*    h_all   = (float*)carve((size_t)Tn*Bn*Un*4);
  float*    decp    = (float*)carve((size_t)Bn*8*256*4);
  float*    c0_all  = (float*)carve((size_t)Tn*Un*4);
  float*    a_all   = (float*)carve((size_t)3200*Sn*4);
  ushort_t* hid_bf  = (ushort_t*)carve((size_t)3200*Un*2);
  ushort_t* W2T     = (ushort_t*)carve((size_t)Vn*Un*2);
  float*    Ssum    = (float*)carve((size_t)3200*4);
  u64*      amax    = (u64*)carve((size_t)3200*8);
  float*    pg      = (float*)carve((size_t)Tn*4);
  float*    psum    = (float*)carve((size_t)Bn*8*4);
  unsigned* bars    = (unsigned*)carve((size_t)Bn*8*32*4);

  hipMemsetAsync(Ssum, 0, 3200*4, stream);
  hipMemsetAsync(amax, 0, 3200*8, stream);
  hipMemsetAsync(bars, 0, Bn*8*32*4, stream);
  hipMemsetAsync(covloss, 0, Bn*Tn*4, stream);

  k_gather<<<3200, 256, 0, stream>>>(gt, emb, Xall);
  k_zx    <<<dim3(50,16), 256, 0, stream>>>(Xall, Wk, lb, Zx);
  k_gpx   <<<Tn, 256, 0, stream>>>(Xall, gpWi, gpbi, gpx);
  k_w2t   <<<dim3(500,4), 256, 0, stream>>>(W2, W2T);

  k_loop  <<<256, 1024, 0, stream>>>(Zx, Wr, Wd, bd, Wc, Wa, enc_attn,
                                     h0, c0, h_all, decp, c0_all,
                                     a_all, covloss, psum, bars);

  k_hid <<<Tn, 256, 0, stream>>>(h_all, W1, b1, hid_bf);
  k_pg  <<<Tn, 256, 0, stream>>>(a_all, enc_out, h_all, c0_all, gpWs, gpWc, gpx, gpWg, pg);
  k_gemm<<<dim3(50,125), 256, 0, stream>>>(hid_bf, W2T, b2, Ssum, amax, pg, probs, 0);
  k_gemm<<<dim3(50,126), 256, 0, stream>>>(hid_bf, W2T, b2, Ssum, amax, pg, probs, 1);
  k_scatter<<<3200, 256, 0, stream>>>(ext, a_all, pg, probs, amax);
  k_seqout <<<13, 256, 0, stream>>>(amax, seqs);
}